// Round 2
// baseline (147.779 us; speedup 1.0000x reference)
//
#include <hip/hip_runtime.h>

#define N_NODES 10000
#define D 128
#define N_EDGES 640000
#define SB 40                  // scan blocks
#define NPSB 250               // nodes per scan block
#define RCB 640                // rank+cast blocks

typedef __attribute__((ext_vector_type(8))) short bf16x8;          // MFMA A/B frag
typedef __attribute__((ext_vector_type(4))) float f32x4;           // MFMA acc
typedef __attribute__((ext_vector_type(8))) unsigned short us8;    // 16B bf16 row chunk
typedef __attribute__((ext_vector_type(8))) float f32x8;

// ---------------- fp32 -> bf16 (round-to-nearest-even) ----------------

__device__ __forceinline__ unsigned short f2bf(float f) {
    union { float f; unsigned int i; } v;
    v.f = f;
    unsigned int b = v.i;
    unsigned int rounded = b + 0x7fffu + ((b >> 16) & 1u);
    return (unsigned short)(rounded >> 16);
}

__device__ __forceinline__ float bf2f(unsigned short u) {
    union { unsigned int i; float f; } v;
    v.i = ((unsigned int)u) << 16;
    return v.f;
}

__device__ __forceinline__ f32x8 bf2f8(us8 v) {
    f32x8 r;
#pragma unroll
    for (int t = 0; t < 8; ++t) r[t] = bf2f(v[t]);
    return r;
}

// ---------------- K1: cast x/W to bf16 + per-edge GLOBAL atomic rank ----------------
// deg[] must be zeroed before launch (hipMemsetAsync in kernel_launch).
// lrank[e] = global rank of edge e within its destination node.

__global__ __launch_bounds__(256) void rank_cast_kernel(const int* __restrict__ ei,
                                                        const float4* __restrict__ x4,
                                                        const float4* __restrict__ Wl4,
                                                        const float4* __restrict__ Wr4,
                                                        ushort4* __restrict__ xh4,
                                                        ushort4* __restrict__ Wlb4,
                                                        ushort4* __restrict__ Wrb4,
                                                        int* __restrict__ deg,
                                                        unsigned short* __restrict__ lrank) {
    const int gid = blockIdx.x * 256 + threadIdx.x;      // 0 .. RCB*256-1 (163840)
    for (int i = gid; i < N_NODES * D / 4; i += RCB * 256) {
        float4 v = x4[i];
        ushort4 o;
        o.x = f2bf(v.x); o.y = f2bf(v.y); o.z = f2bf(v.z); o.w = f2bf(v.w);
        xh4[i] = o;
    }
    if (gid < D * D / 4) {
        float4 a = Wl4[gid], b = Wr4[gid];
        ushort4 oa, ob;
        oa.x = f2bf(a.x); oa.y = f2bf(a.y); oa.z = f2bf(a.z); oa.w = f2bf(a.w);
        ob.x = f2bf(b.x); ob.y = f2bf(b.y); ob.z = f2bf(b.z); ob.w = f2bf(b.w);
        Wlb4[gid] = oa;
        Wrb4[gid] = ob;
    }
    for (int e = gid; e < N_EDGES; e += RCB * 256) {
        int d = ei[N_EDGES + e];                          // row 1 = dst
        lrank[e] = (unsigned short)atomicAdd(&deg[d], 1);
    }
}

// ---------------- K2: block scan of deg + decoupled lookback -> row_start ----------

__global__ __launch_bounds__(256) void scan_kernel(const int* __restrict__ deg,
                                                   int* __restrict__ row_start,
                                                   unsigned long long* __restrict__ flags) {
    const int t = threadIdx.x;
    const int b = blockIdx.x;
    const int n = b * NPSB + t;            // valid for t < NPSB
    __shared__ int sc[256];
    __shared__ int blk_excl_sh;

    int dv = 0;
    if (t < NPSB) dv = deg[n];
    sc[t] = dv;
    __syncthreads();
    for (int off = 1; off < 256; off <<= 1) {
        int v = (t >= off) ? sc[t - off] : 0;
        __syncthreads();
        sc[t] += v;
        __syncthreads();
    }
    const int total = sc[255];
    const int local_excl = sc[t] - dv;

    if (t == 0) {
        int excl = 0;
        if (b == 0) {
            __hip_atomic_store(&flags[0], (2ULL << 32) | (unsigned)total,
                               __ATOMIC_RELEASE, __HIP_MEMORY_SCOPE_AGENT);
        } else {
            __hip_atomic_store(&flags[b], (1ULL << 32) | (unsigned)total,
                               __ATOMIC_RELEASE, __HIP_MEMORY_SCOPE_AGENT);
            int j = b - 1;
            while (j >= 0) {
                unsigned long long f = __hip_atomic_load(&flags[j], __ATOMIC_ACQUIRE,
                                                         __HIP_MEMORY_SCOPE_AGENT);
                unsigned st = (unsigned)(f >> 32);
                if (st == 0) continue;
                excl += (int)(unsigned)(f & 0xffffffffULL);
                if (st == 2) break;
                --j;
            }
            __hip_atomic_store(&flags[b], (2ULL << 32) | (unsigned)(excl + total),
                               __ATOMIC_RELEASE, __HIP_MEMORY_SCOPE_AGENT);
        }
        blk_excl_sh = excl;
    }
    __syncthreads();
    if (t < NPSB) row_start[n] = blk_excl_sh + local_excl;
    if (b == SB - 1 && t == 0) row_start[N_NODES] = N_EDGES;
}

// ---------------- K3: scatter src ids into CSR ----------------

__global__ __launch_bounds__(256) void scatter_kernel(const int* __restrict__ ei,
                                                      const int* __restrict__ row_start,
                                                      const unsigned short* __restrict__ lrank,
                                                      unsigned short* __restrict__ csr) {
    int i = blockIdx.x * 256 + threadIdx.x;
    if (i < N_EDGES) {
        int s = ei[i];
        int d = ei[N_EDGES + i];
        csr[row_start[d] + (int)lrank[i]] = (unsigned short)s;
    }
}

// ---------------- K4: mean aggregation (verified baseline, unchanged) -------------
// block = 128 threads: lane16 = feature octet (16 x 8 = 128 features), slot = 0..7.

__global__ __launch_bounds__(128) void aggregate_kernel(const us8* __restrict__ xh8,
                                                        const int* __restrict__ row_start,
                                                        const unsigned short* __restrict__ csr,
                                                        us8* __restrict__ aggb8) {
    __shared__ unsigned short idxs[256];
    __shared__ f32x8 red[8][16];
    const int node = blockIdx.x;
    const int lane16 = threadIdx.x & 15;   // feature octet
    const int slot = threadIdx.x >> 4;     // edge slot 0..7
    const int start = row_start[node];
    const int end = row_start[node + 1];

    f32x8 a0 = 0.f, a1 = 0.f, a2 = 0.f, a3 = 0.f;
    for (int cs = start; cs < end; cs += 256) {
        int m = min(256, end - cs);
        if ((int)threadIdx.x < m) idxs[threadIdx.x] = csr[cs + threadIdx.x];
        if ((int)threadIdx.x + 128 < m) idxs[threadIdx.x + 128] = csr[cs + threadIdx.x + 128];
        __syncthreads();
        int j = slot;
        for (; j + 24 < m; j += 32) {
            int s0 = idxs[j], s1 = idxs[j + 8], s2 = idxs[j + 16], s3 = idxs[j + 24];
            us8 v0 = xh8[s0 * 16 + lane16];
            us8 v1 = xh8[s1 * 16 + lane16];
            us8 v2 = xh8[s2 * 16 + lane16];
            us8 v3 = xh8[s3 * 16 + lane16];
            a0 += bf2f8(v0); a1 += bf2f8(v1); a2 += bf2f8(v2); a3 += bf2f8(v3);
        }
        for (; j < m; j += 8) {
            us8 v = xh8[(int)idxs[j] * 16 + lane16];
            a0 += bf2f8(v);
        }
        __syncthreads();
    }
    a0 = (a0 + a1) + (a2 + a3);
    red[slot][lane16] = a0;
    __syncthreads();
    if (slot == 0) {
        f32x8 o = red[0][lane16];
#pragma unroll
        for (int s = 1; s < 8; ++s) o += red[s][lane16];
        int cntE = end - start;
        float inv = (cntE > 0) ? 1.0f / (float)cntE : 0.0f;
        us8 pack;
#pragma unroll
        for (int t = 0; t < 8; ++t) pack[t] = f2bf(o[t] * inv);
        aggb8[node * 16 + lane16] = pack;
    }
}

// ---------------- K5: SAGE linear + residual via bf16 MFMA (verified baseline) ----
// One wave per 16x16 C tile; K=256 as 8 chained mfma_f32_16x16x32_bf16.

__global__ __launch_bounds__(256) void lin_mfma_kernel(const float* __restrict__ x,
                                                       const unsigned short* __restrict__ aggb,
                                                       const unsigned short* __restrict__ xh,
                                                       const unsigned short* __restrict__ Wlb,
                                                       const unsigned short* __restrict__ Wrb,
                                                       const float* __restrict__ bl,
                                                       float* __restrict__ out) {
    const int wave = threadIdx.x >> 6;
    const int lane = threadIdx.x & 63;
    const int l15 = lane & 15;
    const int quad = lane >> 4;
    const int mt = blockIdx.x * 4 + wave;            // M-tile 0..624 (10000 = 625*16)
    if (mt >= 625) return;
    const int row0 = mt * 16;
    const int out0 = blockIdx.y * 16;

    const int m = row0 + l15;
    const int f = out0 + l15;

    const bf16x8* arow = (const bf16x8*)(aggb + (size_t)m * D) + quad;
    const bf16x8* xrow = (const bf16x8*)(xh   + (size_t)m * D) + quad;
    const bf16x8* wlro = (const bf16x8*)(Wlb + (size_t)f * D) + quad;
    const bf16x8* wrro = (const bf16x8*)(Wrb + (size_t)f * D) + quad;

    f32x4 c = {0.f, 0.f, 0.f, 0.f};
#pragma unroll
    for (int kk = 0; kk < 4; ++kk) {
        c = __builtin_amdgcn_mfma_f32_16x16x32_bf16(arow[kk * 4], wlro[kk * 4], c, 0, 0, 0);
        c = __builtin_amdgcn_mfma_f32_16x16x32_bf16(xrow[kk * 4], wrro[kk * 4], c, 0, 0, 0);
    }

    const float bias = bl[f];
#pragma unroll
    for (int r = 0; r < 4; ++r) {
        int row = row0 + quad * 4 + r;
        int idx = row * D + f;
        out[idx] = x[idx] + bias + c[r];
    }
}

extern "C" void kernel_launch(void* const* d_in, const int* in_sizes, int n_in,
                              void* d_out, int out_size, void* d_ws, size_t ws_size,
                              hipStream_t stream) {
    const float* x  = (const float*)d_in[0];
    const int*   ei = (const int*)d_in[1];     // [2, E] int32
    const float* Wl = (const float*)d_in[2];
    const float* bl = (const float*)d_in[3];
    const float* Wr = (const float*)d_in[4];
    float* out = (float*)d_out;

    // workspace layout (16B-aligned segments)
    unsigned long long* flags = (unsigned long long*)d_ws;           // 64 ULL (512 B)
    int* deg = (int*)(flags + 64);                                   // 10016 ints
    int* row_start = deg + 10016;                                    // 10016 ints
    unsigned short* lrank = (unsigned short*)(row_start + 10016);    // N_EDGES us
    unsigned short* csr   = lrank + N_EDGES;                         // N_EDGES us
    unsigned short* xh    = csr + N_EDGES;                           // N_NODES*D bf16
    unsigned short* aggb  = xh + (size_t)N_NODES * D;                // N_NODES*D bf16
    unsigned short* Wlb   = aggb + (size_t)N_NODES * D;              // D*D bf16
    unsigned short* Wrb   = Wlb + D * D;                             // D*D bf16

    // zero flags (512 B) + deg (40064 B) -- contiguous at ws start
    hipMemsetAsync(d_ws, 0, 512 + 10016 * 4, stream);

    rank_cast_kernel<<<RCB, 256, 0, stream>>>(ei, (const float4*)x, (const float4*)Wl,
                                              (const float4*)Wr, (ushort4*)xh,
                                              (ushort4*)Wlb, (ushort4*)Wrb, deg, lrank);
    scan_kernel<<<SB, 256, 0, stream>>>(deg, row_start, flags);
    scatter_kernel<<<(N_EDGES + 255) / 256, 256, 0, stream>>>(ei, row_start, lrank, csr);
    aggregate_kernel<<<N_NODES, 128, 0, stream>>>((const us8*)xh, row_start, csr,
                                                  (us8*)aggb);
    lin_mfma_kernel<<<dim3(157, 8), 256, 0, stream>>>(x, aggb, xh, Wlb, Wrb, bl, out);
}

// Round 3
// 128.518 us; speedup vs baseline: 1.1499x; 1.1499x over previous
//
#include <hip/hip_runtime.h>

#define N_NODES 10000
#define D 128
#define N_EDGES 640000
#define NB 128                 // histogram blocks
#define EPB (N_EDGES / NB)     // 5000 edges per block
#define SB 40                  // scan blocks
#define NPSB 250               // nodes per scan block

typedef __attribute__((ext_vector_type(8))) short bf16x8;          // MFMA A/B frag
typedef __attribute__((ext_vector_type(4))) float f32x4;           // MFMA acc
typedef __attribute__((ext_vector_type(8))) unsigned short us8;    // 16B bf16 row chunk
typedef __attribute__((ext_vector_type(8))) float f32x8;

// ---------------- fp32 -> bf16 (round-to-nearest-even) ----------------

__device__ __forceinline__ unsigned short f2bf(float f) {
    union { float f; unsigned int i; } v;
    v.f = f;
    unsigned int b = v.i;
    unsigned int rounded = b + 0x7fffu + ((b >> 16) & 1u);
    return (unsigned short)(rounded >> 16);
}

__device__ __forceinline__ float bf2f(unsigned short u) {
    union { unsigned int i; float f; } v;
    v.i = ((unsigned int)u) << 16;
    return v.f;
}

__device__ __forceinline__ f32x8 bf2f8(us8 v) {
    f32x8 r;
#pragma unroll
    for (int t = 0; t < 8; ++t) r[t] = bf2f(v[t]);
    return r;
}

// ---------------- K1: cast x/W to bf16 + LDS histogram (verified baseline) --------
// cnt is NODE-MAJOR: cnt[n*NB + b] = count of edges->n in histogram block b.

__global__ __launch_bounds__(1024) void hist_cast_kernel(const int* __restrict__ ei,
                                                         const float4* __restrict__ x4,
                                                         const float4* __restrict__ Wl4,
                                                         const float4* __restrict__ Wr4,
                                                         ushort4* __restrict__ xh4,
                                                         ushort4* __restrict__ Wlb4,
                                                         ushort4* __restrict__ Wrb4,
                                                         unsigned short* __restrict__ lrank,
                                                         unsigned short* __restrict__ cnt,
                                                         unsigned long long* __restrict__ flags) {
    __shared__ int h[N_NODES];
    for (int n = threadIdx.x; n < N_NODES; n += 1024) h[n] = 0;
    if (blockIdx.x == 0 && threadIdx.x < SB) flags[threadIdx.x] = 0ULL;

    // cast x (320000 float4 groups) + W (4096 float4 groups) across the whole grid
    const int gid = blockIdx.x * 1024 + threadIdx.x;      // 131072 threads
    for (int i = gid; i < N_NODES * D / 4; i += NB * 1024) {
        float4 v = x4[i];
        ushort4 o;
        o.x = f2bf(v.x); o.y = f2bf(v.y); o.z = f2bf(v.z); o.w = f2bf(v.w);
        xh4[i] = o;
    }
    if (gid < D * D / 4) {
        float4 a = Wl4[gid], b = Wr4[gid];
        ushort4 oa, ob;
        oa.x = f2bf(a.x); oa.y = f2bf(a.y); oa.z = f2bf(a.z); oa.w = f2bf(a.w);
        ob.x = f2bf(b.x); ob.y = f2bf(b.y); ob.z = f2bf(b.z); ob.w = f2bf(b.w);
        Wlb4[gid] = oa;
        Wrb4[gid] = ob;
    }
    __syncthreads();

    const int base = blockIdx.x * EPB;
    for (int e = base + threadIdx.x; e < base + EPB; e += 1024) {
        int d = ei[N_EDGES + e];            // row 1 = dst
        lrank[e] = (unsigned short)atomicAdd(&h[d], 1);
    }
    __syncthreads();
    // node-major write: column blockIdx.x of each node's 128-count row
    for (int n = threadIdx.x; n < N_NODES; n += 1024)
        cnt[(size_t)n * NB + blockIdx.x] = (unsigned short)h[n];
}

// ---------------- K2: in-register per-node scan + decoupled lookback --------------
// One thread per node: 16 x us8 loads (256B contiguous row), 128-step exclusive
// scan in registers (no L2 dependency chain), store back; node total feeds the
// verified block scan + lookback.

__global__ __launch_bounds__(256) void scan_kernel(unsigned short* __restrict__ cnt,
                                                   int* __restrict__ row_start,
                                                   unsigned long long* __restrict__ flags) {
    const int t = threadIdx.x;
    const int b = blockIdx.x;
    const int n = b * NPSB + t;            // valid for t < NPSB
    __shared__ int sc[256];
    __shared__ int blk_excl_sh;

    int deg = 0;
    if (t < NPSB) {
        us8* p = (us8*)(cnt + (size_t)n * NB);
        us8 w[16];
#pragma unroll
        for (int c = 0; c < 16; ++c) w[c] = p[c];       // 16 loads in flight
        int s = 0;
#pragma unroll
        for (int c = 0; c < 16; ++c) {
#pragma unroll
            for (int j = 0; j < 8; ++j) {
                int v = w[c][j];
                w[c][j] = (unsigned short)s;
                s += v;
            }
        }
#pragma unroll
        for (int c = 0; c < 16; ++c) p[c] = w[c];       // write exclusive prefixes
        deg = s;
    }
    sc[t] = deg;
    __syncthreads();
    for (int off = 1; off < 256; off <<= 1) {
        int v = (t >= off) ? sc[t - off] : 0;
        __syncthreads();
        sc[t] += v;
        __syncthreads();
    }
    const int total = sc[255];
    const int local_excl = sc[t] - deg;

    if (t == 0) {
        int excl = 0;
        if (b == 0) {
            __hip_atomic_store(&flags[0], (2ULL << 32) | (unsigned)total,
                               __ATOMIC_RELEASE, __HIP_MEMORY_SCOPE_AGENT);
        } else {
            __hip_atomic_store(&flags[b], (1ULL << 32) | (unsigned)total,
                               __ATOMIC_RELEASE, __HIP_MEMORY_SCOPE_AGENT);
            int j = b - 1;
            while (j >= 0) {
                unsigned long long f = __hip_atomic_load(&flags[j], __ATOMIC_ACQUIRE,
                                                         __HIP_MEMORY_SCOPE_AGENT);
                unsigned st = (unsigned)(f >> 32);
                if (st == 0) continue;
                excl += (int)(unsigned)(f & 0xffffffffULL);
                if (st == 2) break;
                --j;
            }
            __hip_atomic_store(&flags[b], (2ULL << 32) | (unsigned)(excl + total),
                               __ATOMIC_RELEASE, __HIP_MEMORY_SCOPE_AGENT);
        }
        blk_excl_sh = excl;
    }
    __syncthreads();
    if (t < NPSB) row_start[n] = blk_excl_sh + local_excl;
    if (b == SB - 1 && t == 0) row_start[N_NODES] = N_EDGES;
}

// ---------------- K3: scatter src ids into CSR ----------------

__global__ __launch_bounds__(256) void scatter_kernel(const int* __restrict__ ei,
                                                      const int* __restrict__ row_start,
                                                      const unsigned short* __restrict__ cnt,
                                                      const unsigned short* __restrict__ lrank,
                                                      unsigned short* __restrict__ csr) {
    int i = blockIdx.x * 256 + threadIdx.x;
    if (i < N_EDGES) {
        int blk = i / EPB;
        int s = ei[i];
        int d = ei[N_EDGES + i];
        int pos = row_start[d] + (int)cnt[(size_t)d * NB + blk] + (int)lrank[i];
        csr[pos] = (unsigned short)s;
    }
}

// ---------------- K4: mean aggregation (verified baseline, unchanged) -------------
// block = 128 threads: lane16 = feature octet (16 x 8 = 128 features), slot = 0..7.

__global__ __launch_bounds__(128) void aggregate_kernel(const us8* __restrict__ xh8,
                                                        const int* __restrict__ row_start,
                                                        const unsigned short* __restrict__ csr,
                                                        us8* __restrict__ aggb8) {
    __shared__ unsigned short idxs[256];
    __shared__ f32x8 red[8][16];
    const int node = blockIdx.x;
    const int lane16 = threadIdx.x & 15;   // feature octet
    const int slot = threadIdx.x >> 4;     // edge slot 0..7
    const int start = row_start[node];
    const int end = row_start[node + 1];

    f32x8 a0 = 0.f, a1 = 0.f, a2 = 0.f, a3 = 0.f;
    for (int cs = start; cs < end; cs += 256) {
        int m = min(256, end - cs);
        if ((int)threadIdx.x < m) idxs[threadIdx.x] = csr[cs + threadIdx.x];
        if ((int)threadIdx.x + 128 < m) idxs[threadIdx.x + 128] = csr[cs + threadIdx.x + 128];
        __syncthreads();
        int j = slot;
        for (; j + 24 < m; j += 32) {
            int s0 = idxs[j], s1 = idxs[j + 8], s2 = idxs[j + 16], s3 = idxs[j + 24];
            us8 v0 = xh8[s0 * 16 + lane16];
            us8 v1 = xh8[s1 * 16 + lane16];
            us8 v2 = xh8[s2 * 16 + lane16];
            us8 v3 = xh8[s3 * 16 + lane16];
            a0 += bf2f8(v0); a1 += bf2f8(v1); a2 += bf2f8(v2); a3 += bf2f8(v3);
        }
        for (; j < m; j += 8) {
            us8 v = xh8[(int)idxs[j] * 16 + lane16];
            a0 += bf2f8(v);
        }
        __syncthreads();
    }
    a0 = (a0 + a1) + (a2 + a3);
    red[slot][lane16] = a0;
    __syncthreads();
    if (slot == 0) {
        f32x8 o = red[0][lane16];
#pragma unroll
        for (int s = 1; s < 8; ++s) o += red[s][lane16];
        int cntE = end - start;
        float inv = (cntE > 0) ? 1.0f / (float)cntE : 0.0f;
        us8 pack;
#pragma unroll
        for (int t = 0; t < 8; ++t) pack[t] = f2bf(o[t] * inv);
        aggb8[node * 16 + lane16] = pack;
    }
}

// ---------------- K5: SAGE linear + residual via bf16 MFMA (verified baseline) ----
// One wave per 16x16 C tile; K=256 as 8 chained mfma_f32_16x16x32_bf16.

__global__ __launch_bounds__(256) void lin_mfma_kernel(const float* __restrict__ x,
                                                       const unsigned short* __restrict__ aggb,
                                                       const unsigned short* __restrict__ xh,
                                                       const unsigned short* __restrict__ Wlb,
                                                       const unsigned short* __restrict__ Wrb,
                                                       const float* __restrict__ bl,
                                                       float* __restrict__ out) {
    const int wave = threadIdx.x >> 6;
    const int lane = threadIdx.x & 63;
    const int l15 = lane & 15;
    const int quad = lane >> 4;
    const int mt = blockIdx.x * 4 + wave;            // M-tile 0..624 (10000 = 625*16)
    if (mt >= 625) return;
    const int row0 = mt * 16;
    const int out0 = blockIdx.y * 16;

    const int m = row0 + l15;
    const int f = out0 + l15;

    const bf16x8* arow = (const bf16x8*)(aggb + (size_t)m * D) + quad;
    const bf16x8* xrow = (const bf16x8*)(xh   + (size_t)m * D) + quad;
    const bf16x8* wlro = (const bf16x8*)(Wlb + (size_t)f * D) + quad;
    const bf16x8* wrro = (const bf16x8*)(Wrb + (size_t)f * D) + quad;

    f32x4 c = {0.f, 0.f, 0.f, 0.f};
#pragma unroll
    for (int kk = 0; kk < 4; ++kk) {
        c = __builtin_amdgcn_mfma_f32_16x16x32_bf16(arow[kk * 4], wlro[kk * 4], c, 0, 0, 0);
        c = __builtin_amdgcn_mfma_f32_16x16x32_bf16(xrow[kk * 4], wrro[kk * 4], c, 0, 0, 0);
    }

    const float bias = bl[f];
#pragma unroll
    for (int r = 0; r < 4; ++r) {
        int row = row0 + quad * 4 + r;
        int idx = row * D + f;
        out[idx] = x[idx] + bias + c[r];
    }
}

extern "C" void kernel_launch(void* const* d_in, const int* in_sizes, int n_in,
                              void* d_out, int out_size, void* d_ws, size_t ws_size,
                              hipStream_t stream) {
    const float* x  = (const float*)d_in[0];
    const int*   ei = (const int*)d_in[1];     // [2, E] int32
    const float* Wl = (const float*)d_in[2];
    const float* bl = (const float*)d_in[3];
    const float* Wr = (const float*)d_in[4];
    float* out = (float*)d_out;

    // workspace layout (16B-aligned segments)
    unsigned long long* flags = (unsigned long long*)d_ws;               // 64 ULL
    int* row_start = (int*)(flags + 64);                                 // 10016 ints
    unsigned short* cnt   = (unsigned short*)(row_start + 10016);        // N_NODES*NB us (node-major)
    unsigned short* lrank = cnt + (size_t)N_NODES * NB;                  // N_EDGES us
    unsigned short* csr   = lrank + N_EDGES;                             // N_EDGES us
    unsigned short* xh    = csr + N_EDGES;                               // N_NODES*D (bf16)
    unsigned short* aggb  = xh + (size_t)N_NODES * D;                    // N_NODES*D (bf16)
    unsigned short* Wlb   = aggb + (size_t)N_NODES * D;                  // D*D (bf16)
    unsigned short* Wrb   = Wlb + D * D;                                 // D*D (bf16)

    hist_cast_kernel<<<NB, 1024, 0, stream>>>(ei, (const float4*)x, (const float4*)Wl,
                                              (const float4*)Wr, (ushort4*)xh,
                                              (ushort4*)Wlb, (ushort4*)Wrb,
                                              lrank, cnt, flags);
    scan_kernel<<<SB, 256, 0, stream>>>(cnt, row_start, flags);
    scatter_kernel<<<(N_EDGES + 255) / 256, 256, 0, stream>>>(ei, row_start, cnt, lrank, csr);
    aggregate_kernel<<<N_NODES, 128, 0, stream>>>((const us8*)xh, row_start, csr,
                                                  (us8*)aggb);
    lin_mfma_kernel<<<dim3(157, 8), 256, 0, stream>>>(x, aggb, xh, Wlb, Wrb, bl, out);
}